// Round 5
// baseline (189.448 us; speedup 1.0000x reference)
//
#include <hip/hip_runtime.h>
#include <cstdint>
#include <cstddef>

typedef unsigned short u16;
typedef unsigned int   u32;
typedef __attribute__((ext_vector_type(4))) float  f32x4;
typedef __attribute__((ext_vector_type(8))) __bf16 bf16x8;

// ---------------------------------------------------------------------------
// Fully fused: slice + 3x3 conv(+bias,relu) + GEMM (M=32768, K=1024, N=512).
// A-matrix never exists: A-fragments are sliding-window reads of compact
// full-image-conv rows computed in-LDS each K-iteration; slice-boundary cols
// (j=0/31) patched from a 2-value-per-slice side computation (verified r3/r4).
// K-loop: DMA-prefetch tile kk+1 (img rows ring + B dbuf) -> conv kk (hides
// DMA latency) -> barrier -> MFMA kk -> barrier.  ws = 1 MB (lin_w^T only).
// ---------------------------------------------------------------------------

static __device__ __forceinline__ u16 f2b(float f) {
  union { float f; u32 i; } c; c.f = f;
  return (u16)((c.i + 0x7FFFu + ((c.i >> 16) & 1u)) >> 16);  // RNE
}

static __device__ __forceinline__ void gl_lds16(const void* g, void* l) {
  __builtin_amdgcn_global_load_lds(
      (__attribute__((address_space(1))) unsigned int*)(void*)g,
      (__attribute__((address_space(3))) unsigned int*)l, 16, 0, 0);
}

// ---- kernel 0: transpose+cast lin_w (fp32, K=1024 x N=512) -> Bt (bf16, N x K)
__global__ __launch_bounds__(256) void transpose_w(const float* __restrict__ lw,
                                                   u16* __restrict__ bt) {
  __shared__ u16 tile[64][65];
  const int t  = threadIdx.x;
  const int c  = t & 63, r0 = t >> 6;
  const int n0 = blockIdx.x * 64;
  const int k0 = blockIdx.y * 64;
#pragma unroll
  for (int rr = 0; rr < 16; ++rr) {
    const int r = r0 * 16 + rr;
    tile[r][c] = f2b(lw[(size_t)(k0 + r) * 512 + n0 + c]);
  }
  __syncthreads();
#pragma unroll
  for (int rr = 0; rr < 16; ++rr) {
    const int r = r0 * 16 + rr;
    bt[(size_t)(n0 + r) * 1024 + k0 + c] = tile[c][r];
  }
}

// ---- staging helpers for the fused kernel ----------------------------------
// Image row slot: 1056 f32 = padded coords [X0s-4, X0s+1052). 264 16B chunks.
// DMA all chunks with clamped addresses; edge-const chunks overwritten later
// by fix_row (after the drain barrier, before the next reader barrier).
static __device__ __forceinline__ void stage_row_dma(const float* rowg, float* slot,
                                                     int X0s, int t, int w) {
  {
    const int p = X0s - 4 + (t << 2);
    int off = p - 12; off = off < 0 ? 0 : (off > 4092 ? 4092 : off);
    gl_lds16(rowg + off, slot + (w << 8));     // wave-uniform base; lane*16B
  }
  if (t < 8) {
    const int p = X0s - 4 + ((256 + t) << 2);
    int off = p - 12; off = off < 0 ? 0 : (off > 4092 ? 4092 : off);
    gl_lds16(rowg + off, slot + 1024);         // chunks 256..263, lanes 0-7
  }
}
static __device__ __forceinline__ void zero_row(float* slot, int t) {
  const f32x4 z = (f32x4)0.0f;
  *(f32x4*)(slot + (t << 2)) = z;
  if (t < 8) *(f32x4*)(slot + 1024 + (t << 2)) = z;
}
// const chunks: mtm==0 -> ci 0..3 = {0,1,1,1}; mtm==3 -> ci 260..263 = {1,1,1,0}
static __device__ __forceinline__ void fix_row(float* slot, int mtm, int t) {
  if (mtm == 0) {
    if (t < 4) *(f32x4*)(slot + (t << 2)) = (f32x4)(t == 0 ? 0.0f : 1.0f);
  } else if (mtm == 3) {
    if (t < 4) *(f32x4*)(slot + ((260 + t) << 2)) = (f32x4)(t == 3 ? 0.0f : 1.0f);
  }
}
// B tile (128n x 64k bf16) via DMA, XOR-swizzled chunk order (verified r4)
static __device__ __forceinline__ void stage_B(const u16* g, u16* buf, int w) {
  u16* BsW = buf + (w << 11);
  gl_lds16(g,             BsW);
  gl_lds16(g +  8 * 1024, BsW + 512);
  gl_lds16(g + 16 * 1024, BsW + 1024);
  gl_lds16(g + 24 * 1024, BsW + 1536);
}

// conv unit u: 8 outputs of row r at cols c0..c0+7 (full-image conv, verified r3/r4)
static __device__ __forceinline__ void conv_unit(int u, const float* Pm1,
    const float* P0, const float* Pp1, const float* Pp2,
    const float* cwf, float bias, u16* CsA) {
  const int r  = (u >= 131) ? 1 : 0;
  const int c0 = (u - 131 * r) << 3;
  const float* R0 = r ? P0  : Pm1;
  const float* R1 = r ? Pp1 : P0;
  const float* R2 = r ? Pp2 : Pp1;
  float f0[16], f1[16], f2[16];
#pragma unroll
  for (int q = 0; q < 4; ++q) {
    *(f32x4*)&f0[q * 4] = *(const f32x4*)(R0 + c0 + q * 4);
    *(f32x4*)&f1[q * 4] = *(const f32x4*)(R1 + c0 + q * 4);
    *(f32x4*)&f2[q * 4] = *(const f32x4*)(R2 + c0 + q * 4);
  }
  u32 pk[4];
#pragma unroll
  for (int jj = 0; jj < 8; ++jj) {
    float o = bias
        + cwf[0] * f0[jj + 3] + cwf[1] * f0[jj + 4] + cwf[2] * f0[jj + 5]
        + cwf[3] * f1[jj + 3] + cwf[4] * f1[jj + 4] + cwf[5] * f1[jj + 5]
        + cwf[6] * f2[jj + 3] + cwf[7] * f2[jj + 4] + cwf[8] * f2[jj + 5];
    const u32 h = (u32)f2b(fmaxf(o, 0.0f));
    if (jj & 1) pk[jj >> 1] |= h << 16; else pk[jj >> 1] = h;
  }
  *(uint4*)(CsA + r * 1056 + c0) = make_uint4(pk[0], pk[1], pk[2], pk[3]);
}

// ---- the fused kernel ------------------------------------------------------
__global__ __launch_bounds__(256) void fused_gemm(
    const float* __restrict__ img,  // (64,1,32,4096) fp32
    const float* __restrict__ cw,   // (1,1,3,3) fp32
    const float* __restrict__ cb,   // (1,) fp32
    const u16* __restrict__ bt,     // (512,1024) bf16 = lin_w^T
    const float* __restrict__ lb,   // (512,) fp32
    float* __restrict__ out)        // (64,512,512) fp32
{
  // PsF ring 6x1056 f32 (25344B) | Bs dbuf 2x8192 u16 (32768B)
  // CsA 2x1056 u16 (4224B) | Ab32 2x128 u32 (1024B)  => 63360 B total
  __shared__ __align__(16) char smbuf[63360];
  float* PsF  = (float*)smbuf;
  u16*   Bs   = (u16*)(smbuf + 25344);
  u16*   CsA  = (u16*)(smbuf + 58112);
  u32*   Ab32 = (u32*)(smbuf + 62336);
  float* Cs   = (float*)smbuf;              // epilogue reuse [32][132]

  const int t   = threadIdx.x;
  const int nt  = blockIdx.x, mt = blockIdx.y;
  const int b   = mt >> 2, mtm = mt & 3;
  const int n0  = nt << 7;
  const int X0s = mtm << 10;                // first padded X of this M-tile
  const float* imgb = img + (size_t)b * 32 * 4096;

  const int w  = t >> 6, i = t & 63;
  const int wr = w >> 1, wc = w & 1;        // 2x2 wave grid over 128x128
  const int lq = i >> 4, lr = i & 15;

  float cwf[9];
#pragma unroll
  for (int q = 0; q < 9; ++q) cwf[q] = cw[q];
  const float bias = cb[0];

  // B staging ptr: chunk q=w*256+j*64+i -> n=w*32+j*8+(i>>3), swizzled col
  const int cB = (i & 7) ^ ((i >> 3) & 7);
  const u16* btp = bt + (size_t)(n0 + (w << 5) + (i >> 3)) * 1024 + (cB << 3);

  f32x4 acc[4][4];
#pragma unroll
  for (int a = 0; a < 4; ++a)
#pragma unroll
    for (int c = 0; c < 4; ++c) acc[a][c] = (f32x4)0.0f;

  // ---- prologue: rows 0,1,2 (slots 0,1,2), zero row -1 (slot 5), B tile 0
  stage_row_dma(imgb,            PsF,            X0s, t, w);
  stage_row_dma(imgb + 4096,     PsF + 1056,     X0s, t, w);
  stage_row_dma(imgb + 2 * 4096, PsF + 2 * 1056, X0s, t, w);
  stage_B(btp, Bs, w);
  __syncthreads();                          // drain DMA
  zero_row(PsF + 5 * 1056, t);
  fix_row(PsF,            mtm, t);
  fix_row(PsF + 1056,     mtm, t);
  fix_row(PsF + 2 * 1056, mtm, t);
  __syncthreads();

  for (int kk = 0; kk < 16; ++kk) {
    const int base6 = (kk << 1) % 6;
    const int sm1 = (base6 + 5) % 6, sp1 = (base6 + 1) % 6, sp2 = (base6 + 2) % 6;
    const int sa  = (base6 + 3) % 6, sb  = (base6 + 4) % 6;
    const float* Pm1 = PsF + sm1 * 1056;    // row h0-1
    const float* P0  = PsF + base6 * 1056;  // row h0
    const float* Pp1 = PsF + sp1 * 1056;    // row h0+1
    const float* Pp2 = PsF + sp2 * 1056;    // row h0+2

    // -- prefetch tile kk+1 (rows 2kk+3, 2kk+4; B tile kk+1) — lands by barrier A
    if (kk < 15) {
      stage_row_dma(imgb + (2 * kk + 3) * 4096, PsF + sa * 1056, X0s, t, w);
      if (2 * kk + 4 < 32) stage_row_dma(imgb + (2 * kk + 4) * 4096, PsF + sb * 1056, X0s, t, w);
      else                 zero_row(PsF + sb * 1056, t);
      stage_B(btp + ((kk + 1) << 6), Bs + (((kk + 1) & 1) << 13), w);
    }

    // -- conv kk: 2 x 1048 full-conv outputs -> CsA (overlaps DMA latency)
    conv_unit(t, Pm1, P0, Pp1, Pp2, cwf, bias, CsA);
    if (t < 6) conv_unit(256 + t, Pm1, P0, Pp1, Pp2, cwf, bias, CsA);
    // boundary cols j=0 / j=31 per slice -> Ab32 (r = kc row)
    {
      const int r = t >> 7, sp = t & 127;
      const float* R0 = r ? P0  : Pm1;
      const float* R1 = r ? Pp1 : P0;
      const float* R2 = r ? Pp2 : Pp1;
      const f32x4 a0 = *(const f32x4*)(R0 + (sp << 3) + 4);
      const f32x4 a1 = *(const f32x4*)(R1 + (sp << 3) + 4);
      const f32x4 a2 = *(const f32x4*)(R2 + (sp << 3) + 4);
      const f32x4 b0 = *(const f32x4*)(R0 + (sp << 3) + 32);
      const f32x4 b1 = *(const f32x4*)(R1 + (sp << 3) + 32);
      const f32x4 b2 = *(const f32x4*)(R2 + (sp << 3) + 32);
      const float o0 = bias + cwf[1] * a0[0] + cwf[2] * a0[1]
                            + cwf[4] * a1[0] + cwf[5] * a1[1]
                            + cwf[7] * a2[0] + cwf[8] * a2[1];
      const float o1 = bias + cwf[0] * b0[2] + cwf[1] * b0[3]
                            + cwf[3] * b1[2] + cwf[4] * b1[3]
                            + cwf[6] * b2[2] + cwf[7] * b2[3];
      Ab32[(r << 7) + sp] = (u32)f2b(fmaxf(o0, 0.f)) | ((u32)f2b(fmaxf(o1, 0.f)) << 16);
    }

    __syncthreads();   // barrier A: CsA/Ab visible; prefetched DMA drained

    // -- patch edge-const chunks of rows staged this iter (read next iter)
    if (kk < 15) {
      fix_row(PsF + sa * 1056, mtm, t);
      if (2 * kk + 4 < 32) fix_row(PsF + sb * 1056, mtm, t);
    }

    // -- MFMA kk
    const u16* Bsb = Bs + ((kk & 1) << 13);
#pragma unroll
    for (int kc = 0; kc < 2; ++kc) {
      const int bswz = ((((kc << 2) + lq) ^ (lr & 7)) << 3);
      bf16x8 af[4], bfv[4];
#pragma unroll
      for (int im = 0; im < 4; ++im) {
        const int ml = wr * 64 + im * 16 + lr;
        af[im] = __builtin_bit_cast(bf16x8,
            *(const uint4*)(CsA + kc * 1056 + ((ml + lq) << 3)));
        const u32 a32 = Ab32[(kc << 7) + ml];
        union { u16 u; __bf16 h; } lo, hi;
        lo.u = (u16)(a32 & 0xffffu); hi.u = (u16)(a32 >> 16);
        if (lq == 0) af[im][0] = lo.h;      // slice col j=0
        if (lq == 3) af[im][7] = hi.h;      // slice col j=31
      }
#pragma unroll
      for (int jn = 0; jn < 4; ++jn) {
        const int n = wc * 64 + jn * 16 + lr;
        bfv[jn] = __builtin_bit_cast(bf16x8, *(const uint4*)(Bsb + (n << 6) + bswz));
      }
#pragma unroll
      for (int im = 0; im < 4; ++im)
#pragma unroll
        for (int jn = 0; jn < 4; ++jn)
          acc[im][jn] = __builtin_amdgcn_mfma_f32_16x16x32_bf16(
              af[im], bfv[jn], acc[im][jn], 0, 0, 0);
    }

    __syncthreads();   // barrier B: MFMA reads done before next conv/DMA writes
  }

  // ---- epilogue: +lin_b, LDS transpose, coalesced float4 row stores
  float lbv[4];
#pragma unroll
  for (int jn = 0; jn < 4; ++jn) lbv[jn] = lb[n0 + wc * 64 + jn * 16 + lr];

  const int erow = t >> 3, ecol = (t & 7) << 4;
  const int grow_base = (mt << 7) + ((erow >> 4) * 64) + (erow & 15);

#pragma unroll
  for (int im = 0; im < 4; ++im) {
    __syncthreads();
#pragma unroll
    for (int jn = 0; jn < 4; ++jn) {
      const int cl = wc * 64 + jn * 16 + lr;
#pragma unroll
      for (int r = 0; r < 4; ++r)
        Cs[(wr * 16 + lq * 4 + r) * 132 + cl] = acc[im][jn][r] + lbv[jn];
    }
    __syncthreads();
    const size_t grow = (size_t)(grow_base + im * 16);
    float* orow = out + grow * 512 + n0 + ecol;
    const float* crow = Cs + erow * 132 + ecol;
#pragma unroll
    for (int p = 0; p < 4; ++p)
      *(f32x4*)(orow + p * 4) = *(const f32x4*)(crow + p * 4);
  }
}

extern "C" void kernel_launch(void* const* d_in, const int* in_sizes, int n_in,
                              void* d_out, int out_size, void* d_ws, size_t ws_size,
                              hipStream_t stream) {
  const float* img = (const float*)d_in[0];
  const float* cw  = (const float*)d_in[1];
  const float* cb  = (const float*)d_in[2];
  const float* lw  = (const float*)d_in[3];
  const float* lb  = (const float*)d_in[4];
  float* out = (float*)d_out;
  u16* btw = (u16*)d_ws;                    // 1 MB: lin_w^T bf16

  transpose_w<<<dim3(8, 16), 256, 0, stream>>>(lw, btw);
  fused_gemm<<<dim3(4, 256), 256, 0, stream>>>(img, cw, cb, btw, lb, out);
}